// Round 7
// baseline (456.100 us; speedup 1.0000x reference)
//
#include <hip/hip_runtime.h>
#include <hip/hip_bf16.h>

#define BB  64
#define JJ  2048
#define DI  16
#define KC  32
#define DOO 32
#define NKO 1024   // KC*DOO

typedef __bf16 bf16;
typedef __attribute__((ext_vector_type(8))) __bf16 bf16x8;
typedef __attribute__((ext_vector_type(4))) __bf16 bf16x4;
typedef __attribute__((ext_vector_type(4))) float f32x4;

// ---------------- prep: W f32 [J][K][Di][Do] -> bf16 MFMA fragment layout ----------------
// Coalesced float4 reads -> LDS (pad-33 transpose) -> packed bf16x8 fragment stores.
// Fragment layout: elem = j*16384 + t*256 + h2*128 + col*8 + e  holds
//   W[j][ko>>5][i = h2*8 + e][ko&31],  ko = t*16 + col.
__global__ __launch_bounds__(256)
void prep_w2(const float* __restrict__ W, bf16* __restrict__ Wfrag)
{
    __shared__ float wl[8 * 528];   // 8 k-loc x (16 i x 33 pad)
    const int tid = threadIdx.x;
    const int j = blockIdx.x;
    const float* Wj = W + (size_t)j * 16384;
    bf16* Fj = Wfrag + (size_t)j * 16384;

    for (int kg = 0; kg < 4; ++kg) {
#pragma unroll
        for (int it = 0; it < 4; ++it) {
            int q = it * 256 + tid;                 // float4 index < 1024
            float4 v4 = *reinterpret_cast<const float4*>(Wj + (size_t)kg * 4096 + (size_t)q * 4);
            int flat = q * 4;
            int kl = flat >> 9, rem = flat & 511;
            int i = rem >> 5, o = rem & 31;
            float* d = wl + kl * 528 + i * 33 + o;
            d[0] = v4.x; d[1] = v4.y; d[2] = v4.z; d[3] = v4.w;
        }
        __syncthreads();
#pragma unroll
        for (int it = 0; it < 2; ++it) {
            int q = it * 256 + tid;                 // chunk < 512
            int col = q & 15, h2 = (q >> 4) & 1, p = (q >> 5) & 1, kl = q >> 6;
            int t = (kg * 8 + kl) * 2 + p;
            int o = p * 16 + col;
            bf16x8 o8;
#pragma unroll
            for (int e = 0; e < 8; ++e)
                o8[e] = (bf16)wl[kl * 528 + (h2 * 8 + e) * 33 + o];
            *reinterpret_cast<bf16x8*>(Fj + t * 256 + h2 * 128 + col * 8) = o8;
        }
        __syncthreads();
    }
}

// ---------------- prep: X f32 [B][J][Di] -> bf16 fragment layout ----------------
// Xfrag[((j*4 + c)*32 + l)*8 + e] = X[b = c*16 + (l&15)][j][i = (l>>4)*8 + e]
__global__ __launch_bounds__(256)
void prep_x(const float* __restrict__ X, bf16* __restrict__ Xfrag)
{
    int flat = blockIdx.x * 256 + threadIdx.x;        // < 262144
    int l = flat & 31;
    int c = (flat >> 5) & 3;
    int j = flat >> 7;
    int b = c * 16 + (l & 15);
    int i0 = (l >> 4) * 8;
    const float* src = X + ((size_t)b * JJ + j) * DI + i0;
    bf16x8 o8;
#pragma unroll
    for (int e = 0; e < 8; ++e) o8[e] = (bf16)src[e];
    *reinterpret_cast<bf16x8*>(Xfrag + (size_t)flat * 8) = o8;
}

// XCD-aware block decode: the 4 chunk-blocks of one j-range share an XCD L2.
__device__ __forceinline__ void decode_blk(int id, int useXcd, int& c, int& jr)
{
    if (useXcd) { c = (id >> 3) & 3; jr = ((id >> 5) << 3) | (id & 7); }
    else        { c = id & 3;        jr = id >> 2; }
}

// ============ SWAPPED-OPERAND SCHEME ============
// acc[t2] = mfma(A = W tile, B = X chunk): C[row = ko_sub, col = b_local].
// Lane (g = lane>>4, c0 = lane&15): b = chunk*16 + c0, ko = tile*16 + g*4 + r.
// Wave w owns tiles w*4+t2 -> k = w*2 + (t2>>1), o = (t2&1)*16 + g*4 + r.
// => v-dot is lane-local over o (16 FMA) + 2 shfl_xor. Zero LDS bank conflicts.

// ---------------- routing iteration 0 (uniform c = 1/32) ----------------
template<int UF>
__global__ __launch_bounds__(1024, 8)
void caps_init5(const bf16* __restrict__ Xfrag, const bf16* __restrict__ Wfrag,
                const float* __restrict__ Xf, const float* __restrict__ Wf,
                bf16* __restrict__ partial, int Jc)
{
    const int tid  = threadIdx.x;
    const int w    = tid >> 6;
    const int lane = tid & 63;
    const int l5   = lane & 31;
    const bool hi  = lane >= 32;
    int c, jr; decode_blk(blockIdx.x, UF, c, jr);

    const f32x4 ZV = {};
    const bf16x8 ZB = {};
    f32x4 acc[4] = {ZV, ZV, ZV, ZV};

    const int j0 = jr * Jc;
    int jend = j0 + Jc; if (jend > JJ) jend = JJ;

    int j = j0;
    if constexpr (UF) {
        for (; j + 1 < jend; j += 2) {            // lanes>=32 carry j+1 (K rows 16..31)
            const int js = j + (hi ? 1 : 0);
            bf16x8 fx = *reinterpret_cast<const bf16x8*>(
                Xfrag + (((size_t)js * 4 + c) * 32 + l5) * 8);
#pragma unroll
            for (int t2 = 0; t2 < 4; ++t2) {
                bf16x8 fw = *reinterpret_cast<const bf16x8*>(
                    Wfrag + (((size_t)js * 64 + w * 4 + t2) * 32 + l5) * 8);
                acc[t2] = __builtin_amdgcn_mfma_f32_16x16x32_bf16(fw, fx, acc[t2], 0, 0, 0);
            }
        }
    }
    for (; j < jend; ++j) {    // tail / raw-f32 fallback (K rows 16..31 zero)
        bf16x8 fx = ZB;
        if (!hi) {
            if constexpr (UF) {
                fx = *reinterpret_cast<const bf16x8*>(Xfrag + (((size_t)j * 4 + c) * 32 + l5) * 8);
            } else {
                const float* s = Xf + ((size_t)(c * 16 + (l5 & 15)) * JJ + j) * DI + (l5 >> 4) * 8;
#pragma unroll
                for (int e = 0; e < 8; ++e) fx[e] = (bf16)s[e];
            }
        }
#pragma unroll
        for (int t2 = 0; t2 < 4; ++t2) {
            bf16x8 fw = ZB;
            if (!hi) {
                if constexpr (UF) {
                    fw = *reinterpret_cast<const bf16x8*>(
                        Wfrag + (((size_t)j * 64 + w * 4 + t2) * 32 + l5) * 8);
                } else {
                    int ko = (w * 4 + t2) * 16 + (l5 & 15);
                    const float* s = Wf + (size_t)j * 16384 + (size_t)(ko >> 5) * 512
                                   + (size_t)((l5 >> 4) * 8) * 32 + (ko & 31);
#pragma unroll
                    for (int e = 0; e < 8; ++e) fw[e] = (bf16)s[e * 32];
                }
            }
            acc[t2] = __builtin_amdgcn_mfma_f32_16x16x32_bf16(fw, fx, acc[t2], 0, 0, 0);
        }
    }

    bf16* pout = partial + (size_t)jr * (BB * NKO);
#pragma unroll
    for (int t2 = 0; t2 < 4; ++t2) {
        bf16x4 o4;
#pragma unroll
        for (int r = 0; r < 4; ++r) o4[r] = (bf16)(acc[t2][r] * 0.03125f);
        *reinterpret_cast<bf16x4*>(pout + (((size_t)c * 64 + (w * 4 + t2)) * 64 + lane) * 4) = o4;
    }
}

// ---------------- routing iteration 1/2 ----------------
// Phase A: 4 MFMA -> hat (held) -> lane-local v-dot -> 2 shfl_xor/k -> LDS.
// Next-j fragments prefetched before the barriers (register loads don't drain at s_barrier).
// Phase B: softmax over K=32. Phase C: 16 FMA from held hat. VGPR target <= 64 (2 blocks/CU).
template<int UF>
__global__ __launch_bounds__(1024, 8)
void caps_route6(const bf16* __restrict__ Xfrag, const bf16* __restrict__ Wfrag,
                 const float* __restrict__ Xf, const float* __restrict__ Wf,
                 const float* __restrict__ vsum, bf16* __restrict__ partial, int Jc)
{
    __shared__ float clds[2][16][33];

    const int tid  = threadIdx.x;
    const int w    = tid >> 6;
    const int lane = tid & 63;
    const int c0   = lane & 15;
    const int g    = lane >> 4;
    const int l5   = lane & 31;
    const bool lo  = lane < 32;
    int c, jr; decode_blk(blockIdx.x, UF, c, jr);

    const f32x4 ZV = {};
    const bf16x8 ZB = {};
    f32x4 sacc[4] = {ZV, ZV, ZV, ZV};

    const int j0 = jr * Jc;
    int jend = j0 + Jc; if (jend > JJ) jend = JJ;

    // j-invariant vsum base: v[b = c*16+c0][k = w*2 + s][o = h*16 + g*4 + r]
    const float* vb = vsum + ((size_t)(c * 16 + c0) * KC + w * 2) * DOO + g * 4;

    auto load5 = [&](int j, bf16x8& fx, bf16x8& f0, bf16x8& f1, bf16x8& f2, bf16x8& f3) {
        fx = ZB; f0 = ZB; f1 = ZB; f2 = ZB; f3 = ZB;
        if (lo) {
            if constexpr (UF) {
                fx = *reinterpret_cast<const bf16x8*>(Xfrag + (((size_t)j * 4 + c) * 32 + l5) * 8);
                const bf16* wbp = Wfrag + (((size_t)j * 64 + w * 4) * 32 + l5) * 8;
                f0 = *reinterpret_cast<const bf16x8*>(wbp);
                f1 = *reinterpret_cast<const bf16x8*>(wbp + 256);
                f2 = *reinterpret_cast<const bf16x8*>(wbp + 512);
                f3 = *reinterpret_cast<const bf16x8*>(wbp + 768);
            } else {
                const float* s = Xf + ((size_t)(c * 16 + (l5 & 15)) * JJ + j) * DI + (l5 >> 4) * 8;
#pragma unroll
                for (int e = 0; e < 8; ++e) fx[e] = (bf16)s[e];
#pragma unroll
                for (int t2 = 0; t2 < 4; ++t2) {
                    int ko = (w * 4 + t2) * 16 + (l5 & 15);
                    const float* ws = Wf + (size_t)j * 16384 + (size_t)(ko >> 5) * 512
                                    + (size_t)((l5 >> 4) * 8) * 32 + (ko & 31);
                    bf16x8 tmp;
#pragma unroll
                    for (int e = 0; e < 8; ++e) tmp[e] = (bf16)ws[e * 32];
                    if (t2 == 0) f0 = tmp; else if (t2 == 1) f1 = tmp;
                    else if (t2 == 2) f2 = tmp; else f3 = tmp;
                }
            }
        }
    };

    bf16x8 fx, fw0, fw1, fw2, fw3;
    load5(j0, fx, fw0, fw1, fw2, fw3);

    for (int j = j0; j < jend; ++j) {
        const int pb = j & 1;

        // ---- phase A: hat (held through phase C) ----
        f32x4 h0 = __builtin_amdgcn_mfma_f32_16x16x32_bf16(fw0, fx, ZV, 0, 0, 0);
        f32x4 h1 = __builtin_amdgcn_mfma_f32_16x16x32_bf16(fw1, fx, ZV, 0, 0, 0);
        f32x4 h2 = __builtin_amdgcn_mfma_f32_16x16x32_bf16(fw2, fx, ZV, 0, 0, 0);
        f32x4 h3 = __builtin_amdgcn_mfma_f32_16x16x32_bf16(fw3, fx, ZV, 0, 0, 0);

        // ---- prefetch next j's fragments (cur frags now dead) ----
        bf16x8 nfx, nf0, nf1, nf2, nf3;
        load5((j + 1 < jend) ? j + 1 : j, nfx, nf0, nf1, nf2, nf3);

        // ---- lane-local v-dot + 2-shuffle reduce ----
        float4 v0 = *reinterpret_cast<const float4*>(vb);
        float4 v1 = *reinterpret_cast<const float4*>(vb + 16);
        float4 v2 = *reinterpret_cast<const float4*>(vb + 32);
        float4 v3 = *reinterpret_cast<const float4*>(vb + 48);
        float lp0 = h0[0] * v0.x + h0[1] * v0.y + h0[2] * v0.z + h0[3] * v0.w
                  + h1[0] * v1.x + h1[1] * v1.y + h1[2] * v1.z + h1[3] * v1.w;
        float lp1 = h2[0] * v2.x + h2[1] * v2.y + h2[2] * v2.z + h2[3] * v2.w
                  + h3[0] * v3.x + h3[1] * v3.y + h3[2] * v3.z + h3[3] * v3.w;
        lp0 += __shfl_xor(lp0, 16, 64); lp0 += __shfl_xor(lp0, 32, 64);
        lp1 += __shfl_xor(lp1, 16, 64); lp1 += __shfl_xor(lp1, 32, 64);
        if (lane < 16) {
            clds[pb][c0][w * 2]     = lp0;
            clds[pb][c0][w * 2 + 1] = lp1;
        }
        __syncthreads();

        // ---- phase B: softmax over K=32 (16 rows x 32 k = 512 threads) ----
        if (tid < 512) {
            int row = tid >> 5, k = tid & 31;
            float xv = clds[pb][row][k];
            float mx = xv;
#pragma unroll
            for (int m = 1; m < 32; m <<= 1) mx = fmaxf(mx, __shfl_xor(mx, m, 64));
            float ev = __expf(xv - mx);
            float sm = ev;
#pragma unroll
            for (int m = 1; m < 32; m <<= 1) sm += __shfl_xor(sm, m, 64);
            clds[pb][row][k] = ev / sm;
        }
        __syncthreads();

        // ---- phase C: weighted accumulate from held hat (16 FMA) ----
        float cw0 = clds[pb][c0][w * 2];
        float cw1 = clds[pb][c0][w * 2 + 1];
#pragma unroll
        for (int r = 0; r < 4; ++r) {
            sacc[0][r] += cw0 * h0[r];
            sacc[1][r] += cw0 * h1[r];
            sacc[2][r] += cw1 * h2[r];
            sacc[3][r] += cw1 * h3[r];
        }
        fx = nfx; fw0 = nf0; fw1 = nf1; fw2 = nf2; fw3 = nf3;
    }

    bf16* pout = partial + (size_t)jr * (BB * NKO);
#pragma unroll
    for (int t2 = 0; t2 < 4; ++t2) {
        bf16x4 o4;
#pragma unroll
        for (int r = 0; r < 4; ++r) o4[r] = (bf16)sacc[t2][r];
        *reinterpret_cast<bf16x4*>(pout + (((size_t)c * 64 + (w * 4 + t2)) * 64 + lane) * 4) = o4;
    }
}

// ---------------- reduce partials + squash -> v ; update vsum ----------------
// 64-lane group per (c,k): lane (g,c0) holds b=c*16+c0, o = {g*4+r} U {16+g*4+r}.
__global__ __launch_bounds__(256)
void caps_reduce5(const bf16* __restrict__ partial, float* __restrict__ vsum,
                  float* __restrict__ out, int P, int vmode, int wout)
{
    int gt   = blockIdx.x * 256 + threadIdx.x;   // < 8192
    int grp  = gt >> 6;                           // 0..127 = (c, k)
    int lane = gt & 63;
    int c = grp >> 5, k = grp & 31;
    int g = lane >> 4, c0 = lane & 15;

    const bf16* base = partial + ((size_t)(c * 64 + 2 * k) * 64 + lane) * 4;
    float a0[4] = {0.f, 0.f, 0.f, 0.f}, a1[4] = {0.f, 0.f, 0.f, 0.f};
    for (int p = 0; p < P; ++p) {
        bf16x4 v0 = *reinterpret_cast<const bf16x4*>(base + (size_t)p * 65536);
        bf16x4 v1 = *reinterpret_cast<const bf16x4*>(base + 256 + (size_t)p * 65536);
#pragma unroll
        for (int r = 0; r < 4; ++r) { a0[r] += (float)v0[r]; a1[r] += (float)v1[r]; }
    }
    float s2 = 0.f;
#pragma unroll
    for (int r = 0; r < 4; ++r) s2 += a0[r] * a0[r] + a1[r] * a1[r];
    s2 += __shfl_xor(s2, 16, 64);
    s2 += __shfl_xor(s2, 32, 64);
    float scale = s2 / (1.0f + s2) / sqrtf(s2 + 1e-7f);

    int b  = c * 16 + c0;
    int e0 = (b * KC + k) * DOO + g * 4;
    float4 w0, w1;
    w0.x = scale * a0[0]; w0.y = scale * a0[1]; w0.z = scale * a0[2]; w0.w = scale * a0[3];
    w1.x = scale * a1[0]; w1.y = scale * a1[1]; w1.z = scale * a1[2]; w1.w = scale * a1[3];
    if (vmode == 0) {
        *reinterpret_cast<float4*>(vsum + e0)      = w0;
        *reinterpret_cast<float4*>(vsum + e0 + 16) = w1;
    } else if (vmode == 1) {
        float4 o0 = *reinterpret_cast<const float4*>(vsum + e0);
        float4 o1 = *reinterpret_cast<const float4*>(vsum + e0 + 16);
        o0.x += w0.x; o0.y += w0.y; o0.z += w0.z; o0.w += w0.w;
        o1.x += w1.x; o1.y += w1.y; o1.z += w1.z; o1.w += w1.w;
        *reinterpret_cast<float4*>(vsum + e0)      = o0;
        *reinterpret_cast<float4*>(vsum + e0 + 16) = o1;
    }
    if (wout) {
        *reinterpret_cast<float4*>(out + e0)      = w0;
        *reinterpret_cast<float4*>(out + e0 + 16) = w1;
    }
}

extern "C" void kernel_launch(void* const* d_in, const int* in_sizes, int n_in,
                              void* d_out, int out_size, void* d_ws, size_t ws_size,
                              hipStream_t stream)
{
    const float* X  = (const float*)d_in[0];   // [64, 2048, 16] f32
    const float* Wg = (const float*)d_in[1];   // [2048, 32, 16, 32] f32
    float* out = (float*)d_out;                // [64, 32, 32] f32

    const size_t SLICE   = (size_t)BB * NKO;               // 65536 elements
    const size_t WFRAG_B = (size_t)JJ * 64 * 32 * 8 * 2;   // 67108864
    const size_t XFRAG_B = (size_t)JJ * 4 * 32 * 8 * 2;    // 4194304
    const size_t VS_B    = SLICE * sizeof(float);          // 262144

    int P = 128;
    int useFrag = 1;
    bf16 *Wfrag = nullptr, *Xfrag = nullptr, *partial = nullptr;
    float* vsum = nullptr;

    if (ws_size >= WFRAG_B + XFRAG_B + VS_B + (size_t)P * SLICE * 2) {
        Wfrag   = (bf16*)d_ws;
        Xfrag   = (bf16*)((char*)d_ws + WFRAG_B);
        vsum    = (float*)((char*)d_ws + WFRAG_B + XFRAG_B);
        partial = (bf16*)((char*)d_ws + WFRAG_B + XFRAG_B + VS_B);
    } else {
        useFrag = 0;
        size_t avail = (ws_size > VS_B) ? (ws_size - VS_B) / (SLICE * 2) : 1;
        P = (int)avail; if (P < 1) P = 1; if (P > 128) P = 128;
        vsum    = (float*)d_ws;
        partial = (bf16*)((char*)d_ws + VS_B);
    }
    const int Jc = (JJ + P - 1) / P;

    if (useFrag) {
        prep_w2<<<dim3(2048), dim3(256), 0, stream>>>(Wg, Wfrag);
        prep_x<<<dim3(1024),  dim3(256), 0, stream>>>(X,  Xfrag);
        caps_init5<1><<<dim3(4 * P), dim3(1024), 0, stream>>>(Xfrag, Wfrag, X, Wg, partial, Jc);
        caps_reduce5<<<dim3(32), dim3(256), 0, stream>>>(partial, vsum, out, P, 0, 0);
        caps_route6<1><<<dim3(4 * P), dim3(1024), 0, stream>>>(Xfrag, Wfrag, X, Wg, vsum, partial, Jc);
        caps_reduce5<<<dim3(32), dim3(256), 0, stream>>>(partial, vsum, out, P, 1, 0);
        caps_route6<1><<<dim3(4 * P), dim3(1024), 0, stream>>>(Xfrag, Wfrag, X, Wg, vsum, partial, Jc);
        caps_reduce5<<<dim3(32), dim3(256), 0, stream>>>(partial, vsum, out, P, 2, 1);
    } else {
        caps_init5<0><<<dim3(4 * P), dim3(1024), 0, stream>>>(Xfrag, Wfrag, X, Wg, partial, Jc);
        caps_reduce5<<<dim3(32), dim3(256), 0, stream>>>(partial, vsum, out, P, 0, 0);
        caps_route6<0><<<dim3(4 * P), dim3(1024), 0, stream>>>(Xfrag, Wfrag, X, Wg, vsum, partial, Jc);
        caps_reduce5<<<dim3(32), dim3(256), 0, stream>>>(partial, vsum, out, P, 1, 0);
        caps_route6<0><<<dim3(4 * P), dim3(1024), 0, stream>>>(Xfrag, Wfrag, X, Wg, vsum, partial, Jc);
        caps_reduce5<<<dim3(32), dim3(256), 0, stream>>>(partial, vsum, out, P, 2, 1);
    }
}

// Round 8
// 338.023 us; speedup vs baseline: 1.3493x; 1.3493x over previous
//
#include <hip/hip_runtime.h>
#include <hip/hip_bf16.h>

#define BB  64
#define JJ  2048
#define DI  16
#define KC  32
#define DOO 32
#define NKO 1024   // KC*DOO

typedef __bf16 bf16;
typedef __attribute__((ext_vector_type(8))) __bf16 bf16x8;
typedef __attribute__((ext_vector_type(4))) __bf16 bf16x4;
typedef __attribute__((ext_vector_type(2))) __bf16 bf16x2;
typedef __attribute__((ext_vector_type(4))) float f32x4;

// ---------------- prep: W f32 [J][K][Di][Do] -> bf16 MFMA fragment layout ----------------
// Fragment layout: elem = j*16384 + t*256 + h2*128 + col*8 + e  holds
//   W[j][ko>>5][i = h2*8 + e][ko&31],  ko = t*16 + col.
__global__ __launch_bounds__(256)
void prep_w2(const float* __restrict__ W, bf16* __restrict__ Wfrag)
{
    __shared__ float wl[8 * 528];   // 8 k-loc x (16 i x 33 pad)
    const int tid = threadIdx.x;
    const int j = blockIdx.x;
    const float* Wj = W + (size_t)j * 16384;
    bf16* Fj = Wfrag + (size_t)j * 16384;

    for (int kg = 0; kg < 4; ++kg) {
#pragma unroll
        for (int it = 0; it < 4; ++it) {
            int q = it * 256 + tid;                 // float4 index < 1024
            float4 v4 = *reinterpret_cast<const float4*>(Wj + (size_t)kg * 4096 + (size_t)q * 4);
            int flat = q * 4;
            int kl = flat >> 9, rem = flat & 511;
            int i = rem >> 5, o = rem & 31;
            float* d = wl + kl * 528 + i * 33 + o;
            d[0] = v4.x; d[1] = v4.y; d[2] = v4.z; d[3] = v4.w;
        }
        __syncthreads();
#pragma unroll
        for (int it = 0; it < 2; ++it) {
            int q = it * 256 + tid;                 // chunk < 512
            int col = q & 15, h2 = (q >> 4) & 1, p = (q >> 5) & 1, kl = q >> 6;
            int t = (kg * 8 + kl) * 2 + p;
            int o = p * 16 + col;
            bf16x8 o8;
#pragma unroll
            for (int e = 0; e < 8; ++e)
                o8[e] = (bf16)wl[kl * 528 + (h2 * 8 + e) * 33 + o];
            *reinterpret_cast<bf16x8*>(Fj + t * 256 + h2 * 128 + col * 8) = o8;
        }
        __syncthreads();
    }
}

// ---------------- prep: X f32 [B][J][Di] -> bf16 fragment layout ----------------
__global__ __launch_bounds__(256)
void prep_x(const float* __restrict__ X, bf16* __restrict__ Xfrag)
{
    int flat = blockIdx.x * 256 + threadIdx.x;        // < 262144
    int l = flat & 31;
    int c = (flat >> 5) & 3;
    int j = flat >> 7;
    int b = c * 16 + (l & 15);
    int i0 = (l >> 4) * 8;
    const float* src = X + ((size_t)b * JJ + j) * DI + i0;
    bf16x8 o8;
#pragma unroll
    for (int e = 0; e < 8; ++e) o8[e] = (bf16)src[e];
    *reinterpret_cast<bf16x8*>(Xfrag + (size_t)flat * 8) = o8;
}

// XCD-aware block decode (bijective when jr-count % 8 == 0).
__device__ __forceinline__ void decode_blk(int id, int useXcd, int& c, int& jr)
{
    if (useXcd) { c = (id >> 3) & 3; jr = ((id >> 5) << 3) | (id & 7); }
    else        { c = id & 3;        jr = id >> 2; }
}

// Swapped-operand MFMA: mfma(A=W tile, B=X chunk) -> C[row=ko_sub, col=b].
// Lane: b = c*16 + (lane&15), ko = tile*16 + (lane>>4)*4 + r.

// ---------------- routing iteration 0 (uniform c = 1/32) ----------------
template<int UF>
__global__ __launch_bounds__(1024, 8)
void caps_init5(const bf16* __restrict__ Xfrag, const bf16* __restrict__ Wfrag,
                const float* __restrict__ Xf, const float* __restrict__ Wf,
                bf16* __restrict__ partial, int Jc)
{
    const int tid  = threadIdx.x;
    const int w    = tid >> 6;
    const int lane = tid & 63;
    const int l5   = lane & 31;
    const bool hi  = lane >= 32;
    int c, jr; decode_blk(blockIdx.x, UF, c, jr);

    const f32x4 ZV = {};
    const bf16x8 ZB = {};
    f32x4 acc[4] = {ZV, ZV, ZV, ZV};

    const int j0 = jr * Jc;
    int jend = j0 + Jc; if (jend > JJ) jend = JJ;

    int j = j0;
    if constexpr (UF) {
        for (; j + 1 < jend; j += 2) {            // lanes>=32 carry j+1 (K rows 16..31)
            const int js = j + (hi ? 1 : 0);
            bf16x8 fx = *reinterpret_cast<const bf16x8*>(
                Xfrag + (((size_t)js * 4 + c) * 32 + l5) * 8);
#pragma unroll
            for (int t2 = 0; t2 < 4; ++t2) {
                bf16x8 fw = *reinterpret_cast<const bf16x8*>(
                    Wfrag + (((size_t)js * 64 + w * 4 + t2) * 32 + l5) * 8);
                acc[t2] = __builtin_amdgcn_mfma_f32_16x16x32_bf16(fw, fx, acc[t2], 0, 0, 0);
            }
        }
    }
    for (; j < jend; ++j) {
        bf16x8 fx = ZB;
        if (!hi) {
            if constexpr (UF) {
                fx = *reinterpret_cast<const bf16x8*>(Xfrag + (((size_t)j * 4 + c) * 32 + l5) * 8);
            } else {
                const float* s = Xf + ((size_t)(c * 16 + (l5 & 15)) * JJ + j) * DI + (l5 >> 4) * 8;
#pragma unroll
                for (int e = 0; e < 8; ++e) fx[e] = (bf16)s[e];
            }
        }
#pragma unroll
        for (int t2 = 0; t2 < 4; ++t2) {
            bf16x8 fw = ZB;
            if (!hi) {
                if constexpr (UF) {
                    fw = *reinterpret_cast<const bf16x8*>(
                        Wfrag + (((size_t)j * 64 + w * 4 + t2) * 32 + l5) * 8);
                } else {
                    int ko = (w * 4 + t2) * 16 + (l5 & 15);
                    const float* s = Wf + (size_t)j * 16384 + (size_t)(ko >> 5) * 512
                                   + (size_t)((l5 >> 4) * 8) * 32 + (ko & 31);
#pragma unroll
                    for (int e = 0; e < 8; ++e) fw[e] = (bf16)s[e * 32];
                }
            }
            acc[t2] = __builtin_amdgcn_mfma_f32_16x16x32_bf16(fw, fx, acc[t2], 0, 0, 0);
        }
    }

    bf16* pout = partial + (size_t)jr * (BB * NKO);
#pragma unroll
    for (int t2 = 0; t2 < 4; ++t2) {
        bf16x4 o4;
#pragma unroll
        for (int r = 0; r < 4; ++r) o4[r] = (bf16)(acc[t2][r] * 0.03125f);
        *reinterpret_cast<bf16x4*>(pout + (((size_t)c * 64 + (w * 4 + t2)) * 64 + lane) * 4) = o4;
    }
}

// ---------------- A: logits + lane-local softmax (barrier-free) ----------------
// One wave per (j, chunk). Wave computes all 64 tiles (2 MFMA per k), dots with v (bf16),
// 2 shfl per k; all 32 logits live in lane registers -> softmax with NO cross-lane ops.
// Writes c to cbuf[((j*4+c)*16 + b_local)*32 + k], fully coalesced (2KB per wave).
template<int UF>
__global__ __launch_bounds__(256, 4)
void caps_logits(const bf16* __restrict__ Xfrag, const bf16* __restrict__ Wfrag,
                 const float* __restrict__ Xf, const float* __restrict__ Wf,
                 const bf16* __restrict__ vb16, float* __restrict__ cbuf)
{
    const int tid  = threadIdx.x;
    const int w    = tid >> 6;        // wave -> j offset within group
    const int lane = tid & 63;
    const int g    = lane >> 4;
    const int c0   = lane & 15;
    const int l5   = lane & 31;
    const bool lo  = lane < 32;
    int c, jg; decode_blk(blockIdx.x, 1, c, jg);   // 512 j-groups x 4 chunks
    const int j = jg * 4 + w;

    const f32x4 ZV = {};
    const bf16x8 ZB = {};

    bf16x8 fx = ZB;
    if (lo) {
        if constexpr (UF) {
            fx = *reinterpret_cast<const bf16x8*>(Xfrag + (((size_t)j * 4 + c) * 32 + l5) * 8);
        } else {
            const float* s = Xf + ((size_t)(c * 16 + (l5 & 15)) * JJ + j) * DI + (l5 >> 4) * 8;
#pragma unroll
            for (int e = 0; e < 8; ++e) fx[e] = (bf16)s[e];
        }
    }
    const bf16* vbp = vb16 + (size_t)(c * 16 + c0) * (KC * DOO) + g * 4;
    const bf16* wbp = Wfrag + (size_t)j * 16384 + (size_t)l5 * 8;

    float lk[32];
#pragma unroll
    for (int k = 0; k < 32; ++k) {
        bf16x8 fw0 = ZB, fw1 = ZB;
        if (lo) {
            if constexpr (UF) {
                fw0 = *reinterpret_cast<const bf16x8*>(wbp + (size_t)k * 512);
                fw1 = *reinterpret_cast<const bf16x8*>(wbp + (size_t)k * 512 + 256);
            } else {
#pragma unroll
                for (int h = 0; h < 2; ++h) {
                    int ko = (2 * k + h) * 16 + (l5 & 15);
                    const float* ws = Wf + (size_t)j * 16384 + (size_t)(ko >> 5) * 512
                                    + (size_t)((l5 >> 4) * 8) * 32 + (ko & 31);
                    bf16x8 tmp;
#pragma unroll
                    for (int e = 0; e < 8; ++e) tmp[e] = (bf16)ws[e * 32];
                    if (h == 0) fw0 = tmp; else fw1 = tmp;
                }
            }
        }
        f32x4 h0 = __builtin_amdgcn_mfma_f32_16x16x32_bf16(fw0, fx, ZV, 0, 0, 0);
        f32x4 h1 = __builtin_amdgcn_mfma_f32_16x16x32_bf16(fw1, fx, ZV, 0, 0, 0);
        bf16x4 v0 = *reinterpret_cast<const bf16x4*>(vbp + k * 32);
        bf16x4 v1 = *reinterpret_cast<const bf16x4*>(vbp + k * 32 + 16);
        float lp = h0[0] * (float)v0[0] + h0[1] * (float)v0[1]
                 + h0[2] * (float)v0[2] + h0[3] * (float)v0[3]
                 + h1[0] * (float)v1[0] + h1[1] * (float)v1[1]
                 + h1[2] * (float)v1[2] + h1[3] * (float)v1[3];
        lp += __shfl_xor(lp, 16, 64);
        lp += __shfl_xor(lp, 32, 64);
        lk[k] = lp;
    }

    // lane-local softmax over K=32
    float mx = lk[0];
#pragma unroll
    for (int k = 1; k < 32; ++k) mx = fmaxf(mx, lk[k]);
    float sm = 0.f;
#pragma unroll
    for (int k = 0; k < 32; ++k) { lk[k] = __expf(lk[k] - mx); sm += lk[k]; }
    float inv = 1.0f / sm;

    float* cb = cbuf + (((size_t)j * 4 + c) * 16 + c0) * 32;
#pragma unroll
    for (int gg = 0; gg < 4; ++gg) {
        if (g == gg) {   // static lk indices per branch; exec-masked
            float4 f0, f1;
            f0.x = lk[gg * 8 + 0] * inv; f0.y = lk[gg * 8 + 1] * inv;
            f0.z = lk[gg * 8 + 2] * inv; f0.w = lk[gg * 8 + 3] * inv;
            f1.x = lk[gg * 8 + 4] * inv; f1.y = lk[gg * 8 + 5] * inv;
            f1.z = lk[gg * 8 + 6] * inv; f1.w = lk[gg * 8 + 7] * inv;
            *reinterpret_cast<float4*>(cb + gg * 8)     = f0;
            *reinterpret_cast<float4*>(cb + gg * 8 + 4) = f1;
        }
    }
}

// ---------------- B: weighted accumulate (barrier-free, init5-shaped) ----------------
template<int UF>
__global__ __launch_bounds__(1024, 8)
void caps_accum(const bf16* __restrict__ Xfrag, const bf16* __restrict__ Wfrag,
                const float* __restrict__ Xf, const float* __restrict__ Wf,
                const float* __restrict__ cbuf, bf16* __restrict__ partial, int Jc)
{
    const int tid  = threadIdx.x;
    const int w    = tid >> 6;
    const int lane = tid & 63;
    const int c0   = lane & 15;
    const int l5   = lane & 31;
    const bool lo  = lane < 32;
    int c, jr; decode_blk(blockIdx.x, 1, c, jr);

    const f32x4 ZV = {};
    const bf16x8 ZB = {};
    f32x4 sacc[4] = {ZV, ZV, ZV, ZV};

    const int j0 = jr * Jc;
    int jend = j0 + Jc; if (jend > JJ) jend = JJ;

    for (int j = j0; j < jend; ++j) {
        const float* cb = cbuf + (((size_t)j * 4 + c) * 16 + c0) * 32 + w * 2;
        float cw0 = cb[0];
        float cw1 = cb[1];

        bf16x8 fx = ZB, fw0 = ZB, fw1 = ZB, fw2 = ZB, fw3 = ZB;
        if (lo) {
            if constexpr (UF) {
                fx = *reinterpret_cast<const bf16x8*>(Xfrag + (((size_t)j * 4 + c) * 32 + l5) * 8);
                const bf16* wbp = Wfrag + (((size_t)j * 64 + w * 4) * 32 + l5) * 8;
                fw0 = *reinterpret_cast<const bf16x8*>(wbp);
                fw1 = *reinterpret_cast<const bf16x8*>(wbp + 256);
                fw2 = *reinterpret_cast<const bf16x8*>(wbp + 512);
                fw3 = *reinterpret_cast<const bf16x8*>(wbp + 768);
            } else {
                const float* s = Xf + ((size_t)(c * 16 + (l5 & 15)) * JJ + j) * DI + (l5 >> 4) * 8;
#pragma unroll
                for (int e = 0; e < 8; ++e) fx[e] = (bf16)s[e];
#pragma unroll
                for (int t2 = 0; t2 < 4; ++t2) {
                    int ko = (w * 4 + t2) * 16 + (l5 & 15);
                    const float* ws = Wf + (size_t)j * 16384 + (size_t)(ko >> 5) * 512
                                    + (size_t)((l5 >> 4) * 8) * 32 + (ko & 31);
                    bf16x8 tmp;
#pragma unroll
                    for (int e = 0; e < 8; ++e) tmp[e] = (bf16)ws[e * 32];
                    if (t2 == 0) fw0 = tmp; else if (t2 == 1) fw1 = tmp;
                    else if (t2 == 2) fw2 = tmp; else fw3 = tmp;
                }
            }
        }
        f32x4 h;
        h = __builtin_amdgcn_mfma_f32_16x16x32_bf16(fw0, fx, ZV, 0, 0, 0);
#pragma unroll
        for (int r = 0; r < 4; ++r) sacc[0][r] += cw0 * h[r];
        h = __builtin_amdgcn_mfma_f32_16x16x32_bf16(fw1, fx, ZV, 0, 0, 0);
#pragma unroll
        for (int r = 0; r < 4; ++r) sacc[1][r] += cw0 * h[r];
        h = __builtin_amdgcn_mfma_f32_16x16x32_bf16(fw2, fx, ZV, 0, 0, 0);
#pragma unroll
        for (int r = 0; r < 4; ++r) sacc[2][r] += cw1 * h[r];
        h = __builtin_amdgcn_mfma_f32_16x16x32_bf16(fw3, fx, ZV, 0, 0, 0);
#pragma unroll
        for (int r = 0; r < 4; ++r) sacc[3][r] += cw1 * h[r];
    }

    bf16* pout = partial + (size_t)jr * (BB * NKO);
#pragma unroll
    for (int t2 = 0; t2 < 4; ++t2) {
        bf16x4 o4;
#pragma unroll
        for (int r = 0; r < 4; ++r) o4[r] = (bf16)sacc[t2][r];
        *reinterpret_cast<bf16x4*>(pout + (((size_t)c * 64 + (w * 4 + t2)) * 64 + lane) * 4) = o4;
    }
}

// ---------------- reduce stage 1: sum P slices in 8 groups -> tmp f32 [8][65536] ----------------
__global__ __launch_bounds__(256)
void caps_r1(const bf16* __restrict__ partial, float* __restrict__ tmp, int P)
{
    int flat = blockIdx.x * 256 + threadIdx.x;    // < 262144
    int q  = flat >> 15;                          // 0..7
    int e2 = flat & 32767;
    int s  = (P + 7) >> 3;
    int p0 = q * s;
    int p1 = p0 + s; if (p1 > P) p1 = P;
    const bf16* b = partial + (size_t)e2 * 2;
    float s0 = 0.f, s1 = 0.f;
    for (int p = p0; p < p1; ++p) {
        bf16x2 v = *reinterpret_cast<const bf16x2*>(b + (size_t)p * 65536);
        s0 += (float)v[0]; s1 += (float)v[1];
    }
    tmp[(size_t)q * 65536 + e2 * 2]     = s0;
    tmp[(size_t)q * 65536 + e2 * 2 + 1] = s1;
}

// ---------------- reduce stage 2: squash, update vsum (f32) + vb16 (bf16), maybe out ----------------
__global__ __launch_bounds__(256)
void caps_r2(const float* __restrict__ tmp, float* __restrict__ vsum, bf16* __restrict__ vb16,
             float* __restrict__ out, int vmode, int wout)
{
    int gt   = blockIdx.x * 256 + threadIdx.x;   // < 8192
    int grp  = gt >> 6;                           // (c, k)
    int lane = gt & 63;
    int c = grp >> 5, k = grp & 31;
    int g = lane >> 4, c0 = lane & 15;

    size_t base = ((size_t)(c * 64 + 2 * k) * 64 + lane) * 4;
    f32x4 a0 = {}, a1 = {};
#pragma unroll
    for (int p = 0; p < 8; ++p) {
        a0 += *reinterpret_cast<const f32x4*>(tmp + (size_t)p * 65536 + base);
        a1 += *reinterpret_cast<const f32x4*>(tmp + (size_t)p * 65536 + base + 256);
    }
    float s2 = 0.f;
#pragma unroll
    for (int r = 0; r < 4; ++r) s2 += a0[r] * a0[r] + a1[r] * a1[r];
    s2 += __shfl_xor(s2, 16, 64);
    s2 += __shfl_xor(s2, 32, 64);
    float scale = s2 / (1.0f + s2) / sqrtf(s2 + 1e-7f);

    int b  = c * 16 + c0;
    int e0 = (b * KC + k) * DOO + g * 4;
    float w0[4], w1[4], n0[4], n1[4];
#pragma unroll
    for (int r = 0; r < 4; ++r) { w0[r] = scale * a0[r]; w1[r] = scale * a1[r]; }

    if (vmode == 0) {
#pragma unroll
        for (int r = 0; r < 4; ++r) { n0[r] = w0[r]; n1[r] = w1[r]; }
        *reinterpret_cast<float4*>(vsum + e0)      = *reinterpret_cast<float4*>(n0);
        *reinterpret_cast<float4*>(vsum + e0 + 16) = *reinterpret_cast<float4*>(n1);
    } else if (vmode == 1) {
        float4 o0 = *reinterpret_cast<const float4*>(vsum + e0);
        float4 o1 = *reinterpret_cast<const float4*>(vsum + e0 + 16);
        n0[0] = o0.x + w0[0]; n0[1] = o0.y + w0[1]; n0[2] = o0.z + w0[2]; n0[3] = o0.w + w0[3];
        n1[0] = o1.x + w1[0]; n1[1] = o1.y + w1[1]; n1[2] = o1.z + w1[2]; n1[3] = o1.w + w1[3];
        *reinterpret_cast<float4*>(vsum + e0)      = *reinterpret_cast<float4*>(n0);
        *reinterpret_cast<float4*>(vsum + e0 + 16) = *reinterpret_cast<float4*>(n1);
    }
    if (vmode < 2) {     // bf16 copy of the UPDATED running vsum for the next logits pass
        bf16x4 b0, b1;
#pragma unroll
        for (int r = 0; r < 4; ++r) { b0[r] = (bf16)n0[r]; b1[r] = (bf16)n1[r]; }
        *reinterpret_cast<bf16x4*>(vb16 + e0)      = b0;
        *reinterpret_cast<bf16x4*>(vb16 + e0 + 16) = b1;
    }
    if (wout) {
        float4 f0, f1;
        f0.x = w0[0]; f0.y = w0[1]; f0.z = w0[2]; f0.w = w0[3];
        f1.x = w1[0]; f1.y = w1[1]; f1.z = w1[2]; f1.w = w1[3];
        *reinterpret_cast<float4*>(out + e0)      = f0;
        *reinterpret_cast<float4*>(out + e0 + 16) = f1;
    }
}

extern "C" void kernel_launch(void* const* d_in, const int* in_sizes, int n_in,
                              void* d_out, int out_size, void* d_ws, size_t ws_size,
                              hipStream_t stream)
{
    const float* X  = (const float*)d_in[0];   // [64, 2048, 16] f32
    const float* Wg = (const float*)d_in[1];   // [2048, 32, 16, 32] f32
    float* out = (float*)d_out;                // [64, 32, 32] f32

    const size_t WFRAG_B = (size_t)JJ * 64 * 32 * 8 * 2;   // 67108864
    const size_t XFRAG_B = (size_t)JJ * 4 * 32 * 8 * 2;    // 4194304
    const size_t VS_B    = 65536ull * 4;                   // 262144
    const size_t VB_B    = 65536ull * 2;                   // 131072
    const size_t CB_B    = (size_t)BB * JJ * KC * 4;       // 16777216
    const size_t TMP_B   = 8ull * 65536 * 4;               // 2097152
    const size_t FIX_B   = VS_B + VB_B + CB_B + TMP_B;

    int P = 128;
    int useFrag = 1;
    bf16 *Wfrag = nullptr, *Xfrag = nullptr, *partial = nullptr, *vb16 = nullptr;
    float *vsum = nullptr, *cbuf = nullptr, *tmpb = nullptr;

    char* p = (char*)d_ws;
    if (ws_size >= WFRAG_B + XFRAG_B + FIX_B + (size_t)P * 65536 * 2) {
        Wfrag = (bf16*)p;            p += WFRAG_B;
        Xfrag = (bf16*)p;            p += XFRAG_B;
    } else {
        useFrag = 0;
        size_t avail = (ws_size > FIX_B) ? (ws_size - FIX_B) / (65536 * 2) : 8;
        P = (int)(avail & ~7ull);    // keep multiple of 8 for the XCD swizzle
        if (P < 8) P = 8;
        if (P > 128) P = 128;
    }
    vsum    = (float*)p;  p += VS_B;
    vb16    = (bf16*)p;   p += VB_B;
    cbuf    = (float*)p;  p += CB_B;
    tmpb    = (float*)p;  p += TMP_B;
    partial = (bf16*)p;

    const int Jc = (JJ + P - 1) / P;

    if (useFrag) {
        prep_w2<<<dim3(2048), dim3(256), 0, stream>>>(Wg, Wfrag);
        prep_x <<<dim3(1024), dim3(256), 0, stream>>>(X,  Xfrag);

        caps_init5<1><<<dim3(4 * P), dim3(1024), 0, stream>>>(Xfrag, Wfrag, X, Wg, partial, Jc);
        caps_r1<<<dim3(1024), dim3(256), 0, stream>>>(partial, tmpb, P);
        caps_r2<<<dim3(32), dim3(256), 0, stream>>>(tmpb, vsum, vb16, out, 0, 0);

        caps_logits<1><<<dim3(2048), dim3(256), 0, stream>>>(Xfrag, Wfrag, X, Wg, vb16, cbuf);
        caps_accum <1><<<dim3(4 * P), dim3(1024), 0, stream>>>(Xfrag, Wfrag, X, Wg, cbuf, partial, Jc);
        caps_r1<<<dim3(1024), dim3(256), 0, stream>>>(partial, tmpb, P);
        caps_r2<<<dim3(32), dim3(256), 0, stream>>>(tmpb, vsum, vb16, out, 1, 0);

        caps_logits<1><<<dim3(2048), dim3(256), 0, stream>>>(Xfrag, Wfrag, X, Wg, vb16, cbuf);
        caps_accum <1><<<dim3(4 * P), dim3(1024), 0, stream>>>(Xfrag, Wfrag, X, Wg, cbuf, partial, Jc);
        caps_r1<<<dim3(1024), dim3(256), 0, stream>>>(partial, tmpb, P);
        caps_r2<<<dim3(32), dim3(256), 0, stream>>>(tmpb, vsum, vb16, out, 2, 1);
    } else {
        caps_init5<0><<<dim3(4 * P), dim3(1024), 0, stream>>>(Xfrag, Wfrag, X, Wg, partial, Jc);
        caps_r1<<<dim3(1024), dim3(256), 0, stream>>>(partial, tmpb, P);
        caps_r2<<<dim3(32), dim3(256), 0, stream>>>(tmpb, vsum, vb16, out, 0, 0);

        caps_logits<0><<<dim3(2048), dim3(256), 0, stream>>>(Xfrag, Wfrag, X, Wg, vb16, cbuf);
        caps_accum <0><<<dim3(4 * P), dim3(1024), 0, stream>>>(Xfrag, Wfrag, X, Wg, cbuf, partial, Jc);
        caps_r1<<<dim3(1024), dim3(256), 0, stream>>>(partial, tmpb, P);
        caps_r2<<<dim3(32), dim3(256), 0, stream>>>(tmpb, vsum, vb16, out, 1, 0);

        caps_logits<0><<<dim3(2048), dim3(256), 0, stream>>>(Xfrag, Wfrag, X, Wg, vb16, cbuf);
        caps_accum <0><<<dim3(4 * P), dim3(1024), 0, stream>>>(Xfrag, Wfrag, X, Wg, cbuf, partial, Jc);
        caps_r1<<<dim3(1024), dim3(256), 0, stream>>>(partial, tmpb, P);
        caps_r2<<<dim3(32), dim3(256), 0, stream>>>(tmpb, vsum, vb16, out, 2, 1);
    }
}

// Round 9
// 255.991 us; speedup vs baseline: 1.7817x; 1.3205x over previous
//
#include <hip/hip_runtime.h>
#include <hip/hip_bf16.h>

#define BB  64
#define JJ  2048
#define DI  16
#define KC  32
#define DOO 32
#define NKO 1024   // KC*DOO

typedef __bf16 bf16;
typedef __attribute__((ext_vector_type(8)))  __bf16 bf16x8;
typedef __attribute__((ext_vector_type(4)))  __bf16 bf16x4;
typedef __attribute__((ext_vector_type(2)))  __bf16 bf16x2;
typedef __attribute__((ext_vector_type(4)))  float  f32x4;
typedef __attribute__((ext_vector_type(16))) float  f32x16;

// ======== 32x32x16 MFMA scheme ========
// D = A(32x16) * B(16x32).  A = W-slice (rows = o), B = X (cols = b). K = i (16, fully used).
// A-frag: lane l holds row o = l&31, k i = (l>>5)*8 + e   (8 bf16)
// B-frag: lane l holds col b = l&31, k i = (l>>5)*8 + e
// C/D   : col b = lane&31, row o = (reg&3) + 8*(reg>>2) + 4*(lane>>5)   [m74/m101]

// ---------------- prep: W f32 [J][K][Di][Do] -> A-fragment layout ----------------
// Wfrag32[((j*32 + k)*64 + lane)*8 + e] = W[j][k][(lane>>5)*8 + e][lane&31]
__global__ __launch_bounds__(256)
void prep_w3(const float* __restrict__ W, bf16* __restrict__ Wfrag)
{
    __shared__ float wl[8 * 528];   // 8 k x (16 i x 33 pad)
    const int tid = threadIdx.x;
    const int j = blockIdx.x;
    const float* Wj = W + (size_t)j * 16384;
    bf16* Fj = Wfrag + (size_t)j * 16384;

    for (int kg = 0; kg < 4; ++kg) {
#pragma unroll
        for (int it = 0; it < 4; ++it) {
            int q = it * 256 + tid;                 // float4 index < 1024
            float4 v4 = *reinterpret_cast<const float4*>(Wj + (size_t)kg * 4096 + (size_t)q * 4);
            int flat = q * 4;
            int kl = flat >> 9, rem = flat & 511;
            int i = rem >> 5, o = rem & 31;
            float* d = wl + kl * 528 + i * 33 + o;
            d[0] = v4.x; d[1] = v4.y; d[2] = v4.z; d[3] = v4.w;
        }
        __syncthreads();
#pragma unroll
        for (int it = 0; it < 2; ++it) {
            int q = it * 256 + tid;                 // < 512 = 8 k x 64 lanes
            int lane = q & 63, kl = q >> 6;
            int o = lane & 31, hi = lane >> 5;
            bf16x8 o8;
#pragma unroll
            for (int e = 0; e < 8; ++e)
                o8[e] = (bf16)wl[kl * 528 + (hi * 8 + e) * 33 + o];
            *reinterpret_cast<bf16x8*>(Fj + (((size_t)(kg * 8 + kl)) * 64 + lane) * 8) = o8;
        }
        __syncthreads();
    }
}

// ---------------- prep: X f32 [B][J][Di] -> B-fragment layout ----------------
// Xfrag32[((j*2 + c01)*64 + lane)*8 + e] = X[c01*32 + (lane&31)][j][(lane>>5)*8 + e]
__global__ __launch_bounds__(256)
void prep_x3(const float* __restrict__ X, bf16* __restrict__ Xfrag)
{
    int flat = blockIdx.x * 256 + threadIdx.x;    // < 262144
    int lane = flat & 63;
    int c01  = (flat >> 6) & 1;
    int j    = flat >> 7;
    int b    = c01 * 32 + (lane & 31);
    int i0   = (lane >> 5) * 8;
    const float* src = X + ((size_t)b * JJ + j) * DI + i0;
    bf16x8 o8;
#pragma unroll
    for (int e = 0; e < 8; ++e) o8[e] = (bf16)src[e];
    *reinterpret_cast<bf16x8*>(Xfrag + (size_t)flat * 8) = o8;
}

// XCD-aware decodes (bijective for the grids used: 4P with P%8==0, and 1024).
__device__ __forceinline__ void decode_qjr(int id, int& q, int& jr)
{
    q = (id >> 3) & 3; jr = ((id >> 5) << 3) | (id & 7);
}
__device__ __forceinline__ int decode_jg(int id)   // grid 1024
{
    return (id & 7) * 128 + (id >> 3);
}

// ---------------- init / accum: wave = (k, c01) x j-range ----------------
// Block 1024 = 16 waves; grid (4P): q quarter -> unit = q*16 + w; k = unit&31, c01 = unit>>5.
// MODE 0: cw = 1/32 (init). MODE 1: cw = cbuf[(j*32+k)*64 + b] (accum).
template<int UF, int MODE>
__global__ __launch_bounds__(1024, 8)
void caps_mm32(const bf16* __restrict__ Xfrag, const bf16* __restrict__ Wfrag,
               const float* __restrict__ Xf, const float* __restrict__ Wf,
               const float* __restrict__ cbuf, bf16* __restrict__ partial, int Jc)
{
    const int tid  = threadIdx.x;
    const int w    = tid >> 6;
    const int lane = tid & 63;
    const int o31  = lane & 31;
    const int hi   = lane >> 5;
    int q, jr; decode_qjr(blockIdx.x, q, jr);
    const int unit = q * 16 + w;
    const int k    = unit & 31;
    const int c01  = unit >> 5;
    const int b    = c01 * 32 + o31;     // B-frag col for this lane

    const f32x16 ZV16 = {};
    f32x16 acc = ZV16;

    const int j0 = jr * Jc;
    int jend = j0 + Jc; if (jend > JJ) jend = JJ;

    for (int j = j0; j < jend; ++j) {
        bf16x8 fx, fw;
        if constexpr (UF) {
            fx = *reinterpret_cast<const bf16x8*>(Xfrag + (((size_t)j * 2 + c01) * 64 + lane) * 8);
            fw = *reinterpret_cast<const bf16x8*>(Wfrag + (((size_t)j * 32 + k) * 64 + lane) * 8);
        } else {
            const float* xs = Xf + ((size_t)b * JJ + j) * DI + hi * 8;
#pragma unroll
            for (int e = 0; e < 8; ++e) fx[e] = (bf16)xs[e];
            const float* ws = Wf + (size_t)j * 16384 + (size_t)k * 512 + (size_t)(hi * 8) * 32 + o31;
#pragma unroll
            for (int e = 0; e < 8; ++e) fw[e] = (bf16)ws[e * 32];
        }
        if constexpr (MODE == 0) {
            acc = __builtin_amdgcn_mfma_f32_32x32x16_bf16(fw, fx, acc, 0, 0, 0);
        } else {
            float cw = cbuf[((size_t)j * 32 + k) * 64 + b];
            f32x16 h = __builtin_amdgcn_mfma_f32_32x32x16_bf16(fw, fx, ZV16, 0, 0, 0);
#pragma unroll
            for (int r = 0; r < 16; ++r) acc[r] += cw * h[r];
        }
    }

    const float esc = (MODE == 0) ? 0.03125f : 1.0f;
    bf16* pout = partial + (size_t)jr * (BB * NKO);
#pragma unroll
    for (int qq = 0; qq < 4; ++qq) {
        bf16x4 o4;
#pragma unroll
        for (int rr = 0; rr < 4; ++rr) o4[rr] = (bf16)(acc[qq * 4 + rr] * esc);
        *reinterpret_cast<bf16x4*>(pout + (((size_t)unit * 4 + qq) * 64 + lane) * 4) = o4;
    }
}

// ---------------- logits + lane-local softmax ----------------
// Block 256 = 4 waves = (2 j) x (2 c01). Wave: all 32 k, 1 MFMA each; dot vs f32 vsum is
// lane-local over 16 o + ONE shfl_xor(32); softmax fully lane-local; c via LDS transpose.
template<int UF>
__global__ __launch_bounds__(256, 6)
void caps_logits32(const bf16* __restrict__ Xfrag, const bf16* __restrict__ Wfrag,
                   const float* __restrict__ Xf, const float* __restrict__ Wf,
                   const float* __restrict__ vsum, float* __restrict__ cbuf)
{
    __shared__ float cl[2][64][33];

    const int tid  = threadIdx.x;
    const int w    = tid >> 6;
    const int lane = tid & 63;
    const int o31  = lane & 31;          // here doubles as b31
    const int hi   = lane >> 5;
    const int jg   = decode_jg(blockIdx.x);
    const int j0   = jg * 2;
    const int jj   = w >> 1;
    const int c01  = w & 1;
    const int j    = j0 + jj;
    const int b    = c01 * 32 + o31;

    const f32x16 ZV16 = {};

    bf16x8 fx;
    if constexpr (UF) {
        fx = *reinterpret_cast<const bf16x8*>(Xfrag + (((size_t)j * 2 + c01) * 64 + lane) * 8);
    } else {
        const float* xs = Xf + ((size_t)b * JJ + j) * DI + hi * 8;
#pragma unroll
        for (int e = 0; e < 8; ++e) fx[e] = (bf16)xs[e];
    }

    const float* vb = vsum + (size_t)b * NKO + hi * 4;   // + k*32 + q*8 per term
    float lk[32];
#pragma unroll
    for (int k = 0; k < 32; ++k) {
        bf16x8 fw;
        if constexpr (UF) {
            fw = *reinterpret_cast<const bf16x8*>(Wfrag + (((size_t)j * 32 + k) * 64 + lane) * 8);
        } else {
            const float* ws = Wf + (size_t)j * 16384 + (size_t)k * 512 + (size_t)(hi * 8) * 32 + o31;
#pragma unroll
            for (int e = 0; e < 8; ++e) fw[e] = (bf16)ws[e * 32];
        }
        f32x16 h = __builtin_amdgcn_mfma_f32_32x32x16_bf16(fw, fx, ZV16, 0, 0, 0);
        float a = 0.f;
        const float* vk = vb + k * 32;
#pragma unroll
        for (int q = 0; q < 4; ++q) {
            float4 v4 = *reinterpret_cast<const float4*>(vk + q * 8);
            a += h[q * 4 + 0] * v4.x + h[q * 4 + 1] * v4.y
               + h[q * 4 + 2] * v4.z + h[q * 4 + 3] * v4.w;
        }
        a += __shfl_xor(a, 32, 64);
        lk[k] = a;
    }

    // lane-local softmax over K=32
    float mx = lk[0];
#pragma unroll
    for (int k = 1; k < 32; ++k) mx = fmaxf(mx, lk[k]);
    float sm = 0.f;
#pragma unroll
    for (int k = 0; k < 32; ++k) { lk[k] = __expf(lk[k] - mx); sm += lk[k]; }
    float inv = 1.0f / sm;

    if (hi == 0) {
#pragma unroll
        for (int k = 0; k < 32; ++k) cl[jj][b][k] = lk[k] * inv;
    }
    __syncthreads();

    // coalesced c write: cbuf[(j*32 + k)*64 + b]
#pragma unroll
    for (int j2 = 0; j2 < 2; ++j2) {
#pragma unroll
        for (int i = 0; i < 8; ++i) {
            int idx = i * 256 + tid;          // < 2048
            int kk = idx >> 6, bb = idx & 63;
            cbuf[((size_t)(j0 + j2) * 32 + kk) * 64 + bb] = cl[j2][bb][kk];
        }
    }
}

// ---------------- reduce stage 1: sum P slices in 8 groups -> tmp f32 [8][65536] ----------------
__global__ __launch_bounds__(256)
void caps_r1(const bf16* __restrict__ partial, float* __restrict__ tmp, int P)
{
    int flat = blockIdx.x * 256 + threadIdx.x;    // < 262144
    int q  = flat >> 15;                          // 0..7
    int e2 = flat & 32767;
    int s  = (P + 7) >> 3;
    int p0 = q * s;
    int p1 = p0 + s; if (p1 > P) p1 = P;
    const bf16* b = partial + (size_t)e2 * 2;
    float s0 = 0.f, s1 = 0.f;
    for (int p = p0; p < p1; ++p) {
        bf16x2 v = *reinterpret_cast<const bf16x2*>(b + (size_t)p * 65536);
        s0 += (float)v[0]; s1 += (float)v[1];
    }
    tmp[(size_t)q * 65536 + e2 * 2]     = s0;
    tmp[(size_t)q * 65536 + e2 * 2 + 1] = s1;
}

// ---------------- reduce stage 2: squash (o fully lane-local), update vsum / out ----------------
// Thread per (b, k). partial elem ((unit*4+q)*64 + lane)*4 + rr  <->  b = c01*32+(lane&31),
// k = unit&31, o = rr + 8q + 4*(lane>>5).
__global__ __launch_bounds__(64)
void caps_r2(const float* __restrict__ tmp, float* __restrict__ vsum,
             float* __restrict__ out, int vmode, int wout)
{
    int t = blockIdx.x * 64 + threadIdx.x;   // < 2048
    int b31  = t & 31;
    int rest = t >> 5;                        // 0..63
    int k    = rest & 31;
    int c01  = rest >> 5;
    int unit = c01 * 32 + k;

    f32x4 a[8] = {};                          // (q, hi)
#pragma unroll
    for (int p = 0; p < 8; ++p) {
        const float* tp = tmp + (size_t)p * 65536;
#pragma unroll
        for (int q = 0; q < 4; ++q) {
#pragma unroll
            for (int hh = 0; hh < 2; ++hh)
                a[q * 2 + hh] += *reinterpret_cast<const f32x4*>(
                    tp + ((size_t)unit * 4 + q) * 256 + hh * 128 + b31 * 4);
        }
    }
    float s2 = 0.f;
#pragma unroll
    for (int u = 0; u < 8; ++u)
#pragma unroll
        for (int rr = 0; rr < 4; ++rr) s2 += a[u][rr] * a[u][rr];
    float scale = s2 / (1.0f + s2) / sqrtf(s2 + 1e-7f);

    int b  = c01 * 32 + b31;
    size_t e0 = ((size_t)b * KC + k) * DOO;
#pragma unroll
    for (int q = 0; q < 4; ++q) {
#pragma unroll
        for (int hh = 0; hh < 2; ++hh) {
            int o0 = q * 8 + hh * 4;
            float4 wv;
            wv.x = scale * a[q * 2 + hh][0]; wv.y = scale * a[q * 2 + hh][1];
            wv.z = scale * a[q * 2 + hh][2]; wv.w = scale * a[q * 2 + hh][3];
            if (vmode == 0) {
                *reinterpret_cast<float4*>(vsum + e0 + o0) = wv;
            } else if (vmode == 1) {
                float4 ov = *reinterpret_cast<const float4*>(vsum + e0 + o0);
                ov.x += wv.x; ov.y += wv.y; ov.z += wv.z; ov.w += wv.w;
                *reinterpret_cast<float4*>(vsum + e0 + o0) = ov;
            }
            if (wout) *reinterpret_cast<float4*>(out + e0 + o0) = wv;
        }
    }
}

extern "C" void kernel_launch(void* const* d_in, const int* in_sizes, int n_in,
                              void* d_out, int out_size, void* d_ws, size_t ws_size,
                              hipStream_t stream)
{
    const float* X  = (const float*)d_in[0];   // [64, 2048, 16] f32
    const float* Wg = (const float*)d_in[1];   // [2048, 32, 16, 32] f32
    float* out = (float*)d_out;                // [64, 32, 32] f32

    const size_t WFRAG_B = (size_t)JJ * 32 * 64 * 8 * 2;   // 67108864
    const size_t XFRAG_B = (size_t)JJ * 2 * 64 * 8 * 2;    // 4194304
    const size_t VS_B    = 65536ull * 4;                   // 262144
    const size_t CB_B    = (size_t)BB * JJ * KC * 4;       // 16777216
    const size_t TMP_B   = 8ull * 65536 * 4;               // 2097152
    const size_t FIX_B   = VS_B + CB_B + TMP_B;

    int P = 128;
    int useFrag = 1;
    bf16 *Wfrag = nullptr, *Xfrag = nullptr, *partial = nullptr;
    float *vsum = nullptr, *cbuf = nullptr, *tmpb = nullptr;

    char* p = (char*)d_ws;
    if (ws_size >= WFRAG_B + XFRAG_B + FIX_B + (size_t)P * 65536 * 2) {
        Wfrag = (bf16*)p;            p += WFRAG_B;
        Xfrag = (bf16*)p;            p += XFRAG_B;
    } else {
        useFrag = 0;
        size_t avail = (ws_size > FIX_B) ? (ws_size - FIX_B) / (65536 * 2) : 8;
        P = (int)(avail & ~7ull);    // multiple of 8 for the XCD swizzle
        if (P < 8) P = 8;
        if (P > 128) P = 128;
    }
    vsum    = (float*)p;  p += VS_B;
    cbuf    = (float*)p;  p += CB_B;
    tmpb    = (float*)p;  p += TMP_B;
    partial = (bf16*)p;

    const int Jc = (JJ + P - 1) / P;

    if (useFrag) {
        prep_w3<<<dim3(2048), dim3(256), 0, stream>>>(Wg, Wfrag);
        prep_x3<<<dim3(1024), dim3(256), 0, stream>>>(X,  Xfrag);

        caps_mm32<1,0><<<dim3(4 * P), dim3(1024), 0, stream>>>(Xfrag, Wfrag, X, Wg, cbuf, partial, Jc);
        caps_r1<<<dim3(1024), dim3(256), 0, stream>>>(partial, tmpb, P);
        caps_r2<<<dim3(32), dim3(64), 0, stream>>>(tmpb, vsum, out, 0, 0);

        caps_logits32<1><<<dim3(1024), dim3(256), 0, stream>>>(Xfrag, Wfrag, X, Wg, vsum, cbuf);
        caps_mm32<1,1><<<dim3(4 * P), dim3(1024), 0, stream>>>(Xfrag, Wfrag, X, Wg, cbuf, partial, Jc);
        caps_r1<<<dim3(1024), dim3(256), 0, stream>>>(partial, tmpb, P);
        caps_r2<<<dim3(32), dim3(64), 0, stream>>>(tmpb, vsum, out, 1, 0);

        caps_logits32<1><<<dim3(1024), dim3(256), 0, stream>>>(Xfrag, Wfrag, X, Wg, vsum, cbuf);
        caps_mm32<1,1><<<dim3(4 * P), dim3(1024), 0, stream>>>(Xfrag, Wfrag, X, Wg, cbuf, partial, Jc);
        caps_r1<<<dim3(1024), dim3(256), 0, stream>>>(partial, tmpb, P);
        caps_r2<<<dim3(32), dim3(64), 0, stream>>>(tmpb, vsum, out, 2, 1);
    } else {
        caps_mm32<0,0><<<dim3(4 * P), dim3(1024), 0, stream>>>(Xfrag, Wfrag, X, Wg, cbuf, partial, Jc);
        caps_r1<<<dim3(1024), dim3(256), 0, stream>>>(partial, tmpb, P);
        caps_r2<<<dim3(32), dim3(64), 0, stream>>>(tmpb, vsum, out, 0, 0);

        caps_logits32<0><<<dim3(1024), dim3(256), 0, stream>>>(Xfrag, Wfrag, X, Wg, vsum, cbuf);
        caps_mm32<0,1><<<dim3(4 * P), dim3(1024), 0, stream>>>(Xfrag, Wfrag, X, Wg, cbuf, partial, Jc);
        caps_r1<<<dim3(1024), dim3(256), 0, stream>>>(partial, tmpb, P);
        caps_r2<<<dim3(32), dim3(64), 0, stream>>>(tmpb, vsum, out, 1, 0);

        caps_logits32<0><<<dim3(1024), dim3(256), 0, stream>>>(Xfrag, Wfrag, X, Wg, vsum, cbuf);
        caps_mm32<0,1><<<dim3(4 * P), dim3(1024), 0, stream>>>(Xfrag, Wfrag, X, Wg, cbuf, partial, Jc);
        caps_r1<<<dim3(1024), dim3(256), 0, stream>>>(partial, tmpb, P);
        caps_r2<<<dim3(32), dim3(64), 0, stream>>>(tmpb, vsum, out, 2, 1);
    }
}